// Round 10
// baseline (4833.229 us; speedup 1.0000x reference)
//
#include <hip/hip_runtime.h>
#include <hip/hip_bf16.h>

#define SEQ 256
#define NB 16
#define HID 512
#define VOC 32000
#define RSL 16  // local ring slots (skew bound is 1; tags make reuse self-checking)

typedef short bf16x8 __attribute__((ext_vector_type(8)));
typedef float f32x4 __attribute__((ext_vector_type(4)));
typedef unsigned long long u64;

__device__ __forceinline__ void ld_lds16(const void* g, void* l) {
  __builtin_amdgcn_global_load_lds((const __attribute__((address_space(1))) void*)g,
                                   (__attribute__((address_space(3))) void*)l, 16, 0, 0);
}

__device__ __forceinline__ float sigf(float x) { return 1.0f / (1.0f + expf(-x)); }

__device__ __forceinline__ unsigned pk2(float a, float b) {
  __hip_bfloat16 ha = __float2bfloat16(a), hb = __float2bfloat16(b);
  unsigned short ua = *(unsigned short*)&ha, ub = *(unsigned short*)&hb;
  return (unsigned)ua | ((unsigned)ub << 16);
}

__device__ __forceinline__ u64 agload(const u64* p) {
  return __hip_atomic_load(p, __ATOMIC_RELAXED, __HIP_MEMORY_SCOPE_AGENT);
}
__device__ __forceinline__ void agstore(u64* p, u64 v) {
  __hip_atomic_store(p, v, __ATOMIC_RELAXED, __HIP_MEMORY_SCOPE_AGENT);
}

// sc0 load: bypass L1 only, read the XCD-shared L2 (fresh for same-XCD producers).
__device__ __forceinline__ u64 ld_sc0(const u64* p) {
  u64 v;
  asm volatile("global_load_dwordx2 %0, %1, off sc0" : "=v"(v) : "v"(p));
  return v;
}
__device__ __forceinline__ void waitv0() {
  asm volatile("s_waitcnt vmcnt(0)" ::: "memory");
  __builtin_amdgcn_sched_barrier(0);  // rule #18: block MFMA hoist past waitcnt
}

// 32 staged u64 per lane: i -> u64 offset (i>>2)*256 + (i&3)*16 from per-lane base.
__device__ __forceinline__ void load32_sc0(u64* q, const u64* base) {
#pragma unroll
  for (int i = 0; i < 32; ++i) q[i] = ld_sc0(base + (i >> 2) * 256 + (i & 3) * 16);
  waitv0();
}
__device__ __forceinline__ void load32_ag(u64* q, const u64* base) {
#pragma unroll
  for (int i = 0; i < 32; ++i) q[i] = agload(base + (i >> 2) * 256 + (i & 3) * 16);
}
__device__ __forceinline__ bool ok32(const u64* q, unsigned tg) {
  int bad = 0;
#pragma unroll
  for (int i = 0; i < 32; ++i) bad |= ((unsigned)(q[i] >> 32) != tg);
  return !__any(bad);
}
// local-first poll with fabric fallback every 8th round (progress under ANY XCD mapping)
__device__ __forceinline__ void pollLF32(u64* q, const u64* loc, const u64* fab, unsigned tg) {
  load32_sc0(q, loc);
  int rnd = 0;
  while (!ok32(q, tg)) {
    __builtin_amdgcn_s_sleep(1);
    if ((++rnd & 7) == 0) load32_ag(q, fab);
    else load32_sc0(q, loc);
  }
}
__device__ __forceinline__ void pollF32(u64* q, const u64* fab, unsigned tg) {
  load32_ag(q, fab);
  while (!ok32(q, tg)) {
    __builtin_amdgcn_s_sleep(2);
    load32_ag(q, fab);
  }
}

// 8 f32 -> bf16 hi + bf16 lo(residual)
__device__ __forceinline__ void cvt8_hilo(const float* p, bf16x8* h8, bf16x8* l8) {
  union { unsigned short u[8]; bf16x8 v; } uh, ul;
#pragma unroll
  for (int i = 0; i < 8; ++i) {
    float v = p[i];
    __hip_bfloat16 h = __float2bfloat16(v);
    uh.u[i] = *(unsigned short*)&h;
    float rem = v - __bfloat162float(h);
    __hip_bfloat16 l = __float2bfloat16(rem);
    ul.u[i] = *(unsigned short*)&l;
  }
  *h8 = uh.v;
  *l8 = ul.v;
}

// ---------------- embedding gather -> bf16, xe[t*16+b][512] ----------------
__global__ void embed_k(const int* __restrict__ x, const float* __restrict__ emb,
                        unsigned short* __restrict__ xe) {
  int bid = blockIdx.x;  // = t*16 + b
  int t = bid >> 4, b = bid & 15;
  int tok = x[b * SEQ + t];
  const float4* src = (const float4*)(emb + (size_t)tok * HID);
  int e = threadIdx.x;
  float4 a = src[e * 2], c = src[e * 2 + 1];
  uint4 o;
  o.x = pk2(a.x, a.y); o.y = pk2(a.z, a.w);
  o.z = pk2(c.x, c.y); o.w = pk2(c.z, c.w);
  ((uint4*)(xe + (size_t)bid * HID))[e] = o;
}

// ---------------- f32 -> bf16 pack, 8/thread ----------------
__global__ void cvt_k(const float* __restrict__ in, uint4* __restrict__ out) {
  size_t i = (size_t)blockIdx.x * blockDim.x + threadIdx.x;
  const float4* in4 = (const float4*)in;
  float4 a = in4[i * 2], b = in4[i * 2 + 1];
  uint4 o;
  o.x = pk2(a.x, a.y); o.y = pk2(a.z, a.w);
  o.z = pk2(b.x, b.y); o.w = pk2(b.z, b.w);
  out[i] = o;
}

// ---------------- gx GEMM: gx[4096][2048] bf16 = xe @ Wih0^T ----------------
__global__ __launch_bounds__(256) void gx_gemm(const __hip_bfloat16* __restrict__ A,
                                               const __hip_bfloat16* __restrict__ Bw,
                                               unsigned short* __restrict__ C) {
  __shared__ __align__(16) unsigned short lds_a[128 * 32];
  __shared__ __align__(16) unsigned short lds_b[128 * 32];
  const int tid = threadIdx.x;
  const int lane = tid & 63, wid = tid >> 6;
  const int m0 = blockIdx.y * 128, n0 = blockIdx.x * 128;
  const char* Ab = (const char*)A;
  const char* Bb = (const char*)Bw;
  const int ra = tid >> 2, cb = (tid & 3) * 16;
  f32x4 acc[4][4] = {};
  const int wm = (wid >> 1) * 64, wn = (wid & 1) * 64;
  const int fr = lane & 15, fk = (lane >> 4) * 8;
  for (int k0 = 0; k0 < HID; k0 += 32) {
    ld_lds16(Ab + (size_t)(m0 + ra) * 1024 + k0 * 2 + cb, (char*)lds_a + wid * 1024);
    ld_lds16(Ab + (size_t)(m0 + 64 + ra) * 1024 + k0 * 2 + cb, (char*)lds_a + 4096 + wid * 1024);
    ld_lds16(Bb + (size_t)(n0 + ra) * 1024 + k0 * 2 + cb, (char*)lds_b + wid * 1024);
    ld_lds16(Bb + (size_t)(n0 + 64 + ra) * 1024 + k0 * 2 + cb, (char*)lds_b + 4096 + wid * 1024);
    __syncthreads();
    bf16x8 af[4], bf[4];
#pragma unroll
    for (int i = 0; i < 4; ++i) af[i] = *(const bf16x8*)&lds_a[(wm + i * 16 + fr) * 32 + fk];
#pragma unroll
    for (int j = 0; j < 4; ++j) bf[j] = *(const bf16x8*)&lds_b[(wn + j * 16 + fr) * 32 + fk];
#pragma unroll
    for (int i = 0; i < 4; ++i)
#pragma unroll
      for (int j = 0; j < 4; ++j)
        acc[i][j] = __builtin_amdgcn_mfma_f32_16x16x32_bf16(af[i], bf[j], acc[i][j], 0, 0, 0);
    __syncthreads();
  }
  const int cr = (lane >> 4) * 4, cc2 = lane & 15;
#pragma unroll
  for (int i = 0; i < 4; ++i)
#pragma unroll
    for (int jj = 0; jj < 4; ++jj) {
      size_t base = (size_t)(m0 + wm + i * 16 + cr) * 2048 + (n0 + wn + jj * 16 + cc2);
#pragma unroll
      for (int rr = 0; rr < 4; ++rr) {
        __hip_bfloat16 h = __float2bfloat16(acc[i][jj][rr]);
        C[base + (size_t)rr * 2048] = *(unsigned short*)&h;
      }
    }
}

// ---------------- persistent LSTM: XCD-local L2 sync ----------------
// L0: bid%8==0 (XCD0), 32 blocks x 4 waves, wave = 4 cols full-K (Whh0 hi/lo in regs).
//     h0 self-chain: plain store -> L2, sc0 load <- L2. Mirror agent-store to h0fab for L1.
// L1: bid%8==1 (XCD1), 32 blocks x 8 waves = 4 teams x {Wih-wave (h0fab, agent),
//     Whh-wave (h1loc, sc0)}; team reduce via LDS; even wave epilogue + outs.
// u64 = {2 bf16 cols, tag32 = t+1}: single-copy atomic, no fences anywhere.
// Fallback: every 8th poll round reads the fabric mirror -> correct under any mapping.
__global__ __launch_bounds__(512, 2) void lstm_k(
    const float* __restrict__ Wih, const float* __restrict__ Whh,
    const float* __restrict__ bias, const unsigned short* __restrict__ gxb,
    u64* __restrict__ h0loc, u64* __restrict__ h1loc,
    u64* __restrict__ h0fab, u64* __restrict__ h1fab,
    unsigned short* __restrict__ outs) {
  const int bid = blockIdx.x;
  const int sel = bid & 7, r = bid >> 3;
  const int tid = threadIdx.x;
  const int wv = tid >> 6, lane = tid & 63;
  const int b16 = lane & 15, hi = lane >> 4;
  const int qg = b16 & 3, cc = b16 >> 2;  // lane's A-row: gate qg, col-offset cc
  __shared__ __align__(16) float pb[4][64][4];

  if (sel == 0 && r < 32) {
    if (wv >= 4) return;  // L0 uses 4 waves (no __syncthreads in this path)
    const int hc0w = r * 16 + wv * 4;
    bf16x8 Wh[2][16];
    {
      const float* wrow = Whh + (size_t)(qg * HID + hc0w + cc) * HID;
#pragma unroll
      for (int ks = 0; ks < 16; ++ks)
        cvt8_hilo(wrow + ks * 32 + hi * 8, &Wh[0][ks], &Wh[1][ks]);
    }
    float bq[4];
#pragma unroll
    for (int qq = 0; qq < 4; ++qq) bq[qq] = bias[qq * HID + hc0w + hi];
    float c_reg = 0.f;
    const int lbase = hi * 64 + b16;
    u64 qa[32];
#pragma unroll 1
    for (int t = 0; t < SEQ; ++t) {
      float gxr[4];
      {
        const unsigned short* gp = gxb + (size_t)(t * 16 + b16) * 2048 + hc0w + hi;
#pragma unroll
        for (int qq = 0; qq < 4; ++qq) {
          union { unsigned u; float f; } cv;
          cv.u = (unsigned)gp[qq * HID] << 16;
          gxr[qq] = cv.f;
          asm volatile("" : "+v"(gxr[qq]));
        }
      }
      const u64* loc = h0loc + (size_t)(t & (RSL - 1)) * 4096 + lbase;
      const u64* fab = h0fab + (size_t)t * 4096 + lbase;
      f32x4 a0 = {0.f, 0.f, 0.f, 0.f}, a1 = a0, a2 = a0, a3 = a0;
#pragma unroll 1
      for (int h = 0; h < 2; ++h) {
        pollLF32(qa, loc + h * 2048, fab + h * 2048, (unsigned)t);
#pragma unroll
        for (int k2 = 0; k2 < 8; ++k2) {
          union { unsigned u[4]; bf16x8 v; } bb;
#pragma unroll
          for (int j = 0; j < 4; ++j) bb.u[j] = (unsigned)qa[k2 * 4 + j];
          const int ks = h * 8 + k2;
          if (k2 & 1) {
            a2 = __builtin_amdgcn_mfma_f32_16x16x32_bf16(Wh[0][ks], bb.v, a2, 0, 0, 0);
            a3 = __builtin_amdgcn_mfma_f32_16x16x32_bf16(Wh[1][ks], bb.v, a3, 0, 0, 0);
          } else {
            a0 = __builtin_amdgcn_mfma_f32_16x16x32_bf16(Wh[0][ks], bb.v, a0, 0, 0, 0);
            a1 = __builtin_amdgcn_mfma_f32_16x16x32_bf16(Wh[1][ks], bb.v, a1, 0, 0, 0);
          }
        }
      }
      f32x4 acc = (a0 + a2) + (a1 + a3);
      float pre[4];
#pragma unroll
      for (int qq = 0; qq < 4; ++qq) pre[qq] = bq[qq] + gxr[qq] + acc[qq];
      float iv = sigf(pre[0]), fv = sigf(pre[1]);
      float gv = tanhf(pre[2]), ov = sigf(pre[3]);
      c_reg = fv * c_reg + iv * gv;
      float hn = ov * tanhf(c_reg);
      __hip_bfloat16 hh = __float2bfloat16(hn);
      int hb = (int)*(unsigned short*)&hh;
      int pr = __shfl_xor(hb, 16, 64);  // partner col (hi^1)
      unsigned d32 = (unsigned)(unsigned short)hb | ((unsigned)(unsigned short)pr << 16);
      u64 val = (u64)d32 | ((u64)(unsigned)(t + 1) << 32);
      if ((hi & 1) == 0) {
        const int cp = (hc0w + hi) >> 1;
        *(volatile u64*)(h0loc + (size_t)((t + 1) & (RSL - 1)) * 4096 + cp * 16 + b16) = val;
        agstore(h0fab + (size_t)(t + 1) * 4096 + cp * 16 + b16, val);
      }
    }
  } else if (sel == 1 && r < 32) {
    const int tt = wv >> 1;
    const bool whh = (wv & 1) != 0;
    const int hc0t = r * 16 + tt * 4;
    bf16x8 W[2][16];
    {
      const float* wrow = (whh ? Whh : Wih) + (size_t)(2048 + qg * HID + hc0t + cc) * HID;
#pragma unroll
      for (int ks = 0; ks < 16; ++ks)
        cvt8_hilo(wrow + ks * 32 + hi * 8, &W[0][ks], &W[1][ks]);
    }
    float bq[4];
#pragma unroll
    for (int qq = 0; qq < 4; ++qq) bq[qq] = bias[2048 + qq * HID + hc0t + hi];
    float c_reg = 0.f;
    const int lbase = hi * 64 + b16;
    u64 qa[32];
#pragma unroll 1
    for (int t = 0; t < SEQ; ++t) {
      f32x4 a0 = {0.f, 0.f, 0.f, 0.f}, a1 = a0, a2 = a0, a3 = a0;
      const unsigned tg = whh ? (unsigned)t : (unsigned)(t + 1);
      const u64* fab = (whh ? (h1fab + (size_t)t * 4096)
                            : (h0fab + (size_t)(t + 1) * 4096)) + lbase;
      const u64* loc = h1loc + (size_t)(t & (RSL - 1)) * 4096 + lbase;
#pragma unroll 1
      for (int h = 0; h < 2; ++h) {
        if (whh) pollLF32(qa, loc + h * 2048, fab + h * 2048, tg);
        else pollF32(qa, fab + h * 2048, tg);
#pragma unroll
        for (int k2 = 0; k2 < 8; ++k2) {
          union { unsigned u[4]; bf16x8 v; } bb;
#pragma unroll
          for (int j = 0; j < 4; ++j) bb.u[j] = (unsigned)qa[k2 * 4 + j];
          const int ks = h * 8 + k2;
          if (k2 & 1) {
            a2 = __builtin_amdgcn_mfma_f32_16x16x32_bf16(W[0][ks], bb.v, a2, 0, 0, 0);
            a3 = __builtin_amdgcn_mfma_f32_16x16x32_bf16(W[1][ks], bb.v, a3, 0, 0, 0);
          } else {
            a0 = __builtin_amdgcn_mfma_f32_16x16x32_bf16(W[0][ks], bb.v, a0, 0, 0, 0);
            a1 = __builtin_amdgcn_mfma_f32_16x16x32_bf16(W[1][ks], bb.v, a1, 0, 0, 0);
          }
        }
      }
      f32x4 acc = (a0 + a2) + (a1 + a3);
      if (whh) *(f32x4*)&pb[tt][lane][0] = acc;
      __syncthreads();
      if (!whh) {
        f32x4 part = *(f32x4*)&pb[tt][lane][0];
        float pre[4];
#pragma unroll
        for (int qq = 0; qq < 4; ++qq) pre[qq] = bq[qq] + acc[qq] + part[qq];
        float iv = sigf(pre[0]), fv = sigf(pre[1]);
        float gv = tanhf(pre[2]), ov = sigf(pre[3]);
        c_reg = fv * c_reg + iv * gv;
        float hn = ov * tanhf(c_reg);
        __hip_bfloat16 hh = __float2bfloat16(hn);
        int hb = (int)*(unsigned short*)&hh;
        int pr = __shfl_xor(hb, 16, 64);
        unsigned d32 = (unsigned)(unsigned short)hb | ((unsigned)(unsigned short)pr << 16);
        u64 val = (u64)d32 | ((u64)(unsigned)(t + 1) << 32);
        if ((hi & 1) == 0) {
          const int cp = (hc0t + hi) >> 1;
          *(volatile u64*)(h1loc + (size_t)((t + 1) & (RSL - 1)) * 4096 + cp * 16 + b16) = val;
          agstore(h1fab + (size_t)(t + 1) * 4096 + cp * 16 + b16, val);
        }
        unsigned d23 = (unsigned)__shfl((int)d32, b16 + 32, 64);  // cols +2,+3
        if (hi == 0)
          *(u64*)(outs + (size_t)(t * 16 + b16) * 512 + hc0t) = (u64)d32 | ((u64)d23 << 32);
      }
      __syncthreads();
    }
  }
}

// ---------------- FC GEMM: out[b][t][32000] = outs[t*16+b][:] @ fcw^T + fcb ----------------
__global__ __launch_bounds__(256) void fc_gemm(const __hip_bfloat16* __restrict__ A,
                                               const __hip_bfloat16* __restrict__ Bw,
                                               const float* __restrict__ bias,
                                               float* __restrict__ C) {
  __shared__ __align__(16) unsigned short lds_a[128 * 32];
  __shared__ __align__(16) unsigned short lds_b[128 * 32];
  const int tid = threadIdx.x;
  const int lane = tid & 63, wid = tid >> 6;
  const int m0 = blockIdx.y * 128, n0 = blockIdx.x * 128;
  const char* Ab = (const char*)A;
  const char* Bb = (const char*)Bw;
  const int ra = tid >> 2, cb = (tid & 3) * 16;
  f32x4 acc[4][4] = {};
  const int wm = (wid >> 1) * 64, wn = (wid & 1) * 64;
  const int fr = lane & 15, fk = (lane >> 4) * 8;
  for (int k0 = 0; k0 < HID; k0 += 32) {
    ld_lds16(Ab + (size_t)(m0 + ra) * 1024 + k0 * 2 + cb, (char*)lds_a + wid * 1024);
    ld_lds16(Ab + (size_t)(m0 + 64 + ra) * 1024 + k0 * 2 + cb, (char*)lds_a + 4096 + wid * 1024);
    ld_lds16(Bb + (size_t)(n0 + ra) * 1024 + k0 * 2 + cb, (char*)lds_b + wid * 1024);
    ld_lds16(Bb + (size_t)(n0 + 64 + ra) * 1024 + k0 * 2 + cb, (char*)lds_b + 4096 + wid * 1024);
    __syncthreads();
    bf16x8 af[4], bf[4];
#pragma unroll
    for (int i = 0; i < 4; ++i) af[i] = *(const bf16x8*)&lds_a[(wm + i * 16 + fr) * 32 + fk];
#pragma unroll
    for (int j = 0; j < 4; ++j) bf[j] = *(const bf16x8*)&lds_b[(wn + j * 16 + fr) * 32 + fk];
#pragma unroll
    for (int i = 0; i < 4; ++i)
#pragma unroll
      for (int j = 0; j < 4; ++j)
        acc[i][j] = __builtin_amdgcn_mfma_f32_16x16x32_bf16(af[i], bf[j], acc[i][j], 0, 0, 0);
    __syncthreads();
  }
  const int cr = (lane >> 4) * 4, cc2 = lane & 15;
  float bv[4];
#pragma unroll
  for (int jj = 0; jj < 4; ++jj) bv[jj] = bias[n0 + wn + jj * 16 + cc2];
#pragma unroll
  for (int i = 0; i < 4; ++i) {
#pragma unroll
    for (int jj = 0; jj < 4; ++jj) {
#pragma unroll
      for (int rr = 0; rr < 4; ++rr) {
        int tok = m0 + wm + i * 16 + cr + rr;      // = t*16 + b
        int orow = (tok & 15) * SEQ + (tok >> 4);  // = b*256 + t
        C[(size_t)orow * VOC + (n0 + wn + jj * 16 + cc2)] = acc[i][jj][rr] + bv[jj];
      }
    }
  }
}

extern "C" void kernel_launch(void* const* d_in, const int* in_sizes, int n_in,
                              void* d_out, int out_size, void* d_ws, size_t ws_size,
                              hipStream_t stream) {
  const int* x = (const int*)d_in[0];
  const float* emb = (const float*)d_in[1];
  const float* Wih = (const float*)d_in[2];
  const float* Whh = (const float*)d_in[3];
  const float* bias = (const float*)d_in[4];
  const float* fcw = (const float*)d_in[5];
  const float* fcb = (const float*)d_in[6];
  float* out = (float*)d_out;
  char* ws = (char*)d_ws;

  // ws layout (bytes), total 40,960,000:
  //   [0, 4194304)            xe[4096][512] bf16 -> reused as outs after gx_gemm
  //   [4194304, 4718592)      h0loc: 16 slots x 32KB (XCD0-local ring)
  //   [4718592, 5242880)      h1loc: 16 slots x 32KB (XCD1-local ring)
  //   [5242880, 13664256)     h0fab: 257 slots x 32KB (fabric mirror)
  //   [13664256, 22085632)    h1fab: 257 slots x 32KB (fabric mirror)
  //   [22085632, 24182784)    wih0 bf16 [2048][512]   (dead after gx_gemm)
  //   [24182784, 40960000)    gx bf16 [4096][2048]    (dead after lstm_k)
  //   fcw_bf aliases [4194304, 36962304) (rings+wih0+gx head), written after lstm_k
  unsigned short* xe = (unsigned short*)ws;
  unsigned short* outs = (unsigned short*)ws;
  u64* h0loc = (u64*)(ws + 4194304);
  u64* h1loc = (u64*)(ws + 4718592);
  u64* h0fab = (u64*)(ws + 5242880);
  u64* h1fab = (u64*)(ws + 13664256);
  uint4* wih0_bf = (uint4*)(ws + 22085632);
  unsigned short* gxb = (unsigned short*)(ws + 24182784);
  uint4* fcw_bf = (uint4*)(ws + 4194304);

  hipMemsetAsync(ws + 4194304, 0, 17891328, stream);  // all rings: tags=0, h[-1]=0
  embed_k<<<SEQ * NB, 64, 0, stream>>>(x, emb, xe);
  cvt_k<<<512, 256, 0, stream>>>(Wih, wih0_bf);  // layer-0 Wih (1M elems)
  gx_gemm<<<dim3(16, 32), 256, 0, stream>>>((const __hip_bfloat16*)xe,
                                            (const __hip_bfloat16*)wih0_bf, gxb);
  lstm_k<<<256, 512, 0, stream>>>(Wih, Whh, bias, gxb, h0loc, h1loc, h0fab, h1fab, outs);
  cvt_k<<<8000, 256, 0, stream>>>(fcw, fcw_bf);  // aliases rings/wih0/gx (dead after lstm)
  fc_gemm<<<dim3(250, 32), 256, 0, stream>>>((const __hip_bfloat16*)outs,
                                             (const __hip_bfloat16*)fcw_bf, fcb, out);
}

// Round 11
// 1552.720 us; speedup vs baseline: 3.1128x; 3.1128x over previous
//
#include <hip/hip_runtime.h>
#include <hip/hip_bf16.h>

#define SEQ 256
#define NB 16
#define HID 512
#define VOC 32000

typedef short bf16x8 __attribute__((ext_vector_type(8)));
typedef float f32x4 __attribute__((ext_vector_type(4)));
typedef unsigned long long u64;

__device__ __forceinline__ void ld_lds16(const void* g, void* l) {
  __builtin_amdgcn_global_load_lds((const __attribute__((address_space(1))) void*)g,
                                   (__attribute__((address_space(3))) void*)l, 16, 0, 0);
}

__device__ __forceinline__ unsigned pk2(float a, float b) {
  __hip_bfloat16 ha = __float2bfloat16(a), hb = __float2bfloat16(b);
  unsigned short ua = *(unsigned short*)&ha, ub = *(unsigned short*)&hb;
  return (unsigned)ua | ((unsigned)ub << 16);
}

__device__ __forceinline__ u64 agload(const u64* p) {
  return __hip_atomic_load(p, __ATOMIC_RELAXED, __HIP_MEMORY_SCOPE_AGENT);
}
__device__ __forceinline__ void agstore(u64* p, u64 v) {
  __hip_atomic_store(p, v, __ATOMIC_RELAXED, __HIP_MEMORY_SCOPE_AGENT);
}

// fast transcendentals (v_exp_f32 = 2^x, v_rcp_f32): ~1 ulp, correct +-inf limits
__device__ __forceinline__ float fexp2(float x) {
  float r;
  asm("v_exp_f32 %0, %1" : "=v"(r) : "v"(x));
  return r;
}
__device__ __forceinline__ float frcp(float x) {
  float r;
  asm("v_rcp_f32 %0, %1" : "=v"(r) : "v"(x));
  return r;
}
__device__ __forceinline__ float fsig(float x) {
  return frcp(1.f + fexp2(-1.44269504f * x));
}
__device__ __forceinline__ float ftanh(float x) {
  return 1.f - 2.f * frcp(1.f + fexp2(2.88539008f * x));
}

// 16 staging u64s per lane: chunk s (0..3), j (0..3); addr = base + s*256 + j*16 (u64 units)
__device__ __forceinline__ void issue16(u64* q, const u64* base) {
#pragma unroll
  for (int s = 0; s < 4; ++s)
#pragma unroll
    for (int j = 0; j < 4; ++j) q[s * 4 + j] = agload(base + s * 256 + j * 16);
}
__device__ __forceinline__ void revalidate16(u64* q, const u64* base, unsigned tg) {
  for (;;) {
    int bad = 0;
#pragma unroll
    for (int i = 0; i < 16; ++i) bad |= ((unsigned)(q[i] >> 32) != tg);
    if (!__any(bad)) break;
    __builtin_amdgcn_s_sleep(1);
#pragma unroll
    for (int i = 0; i < 16; ++i)
      if ((unsigned)(q[i] >> 32) != tg)
        q[i] = agload(base + (i >> 2) * 256 + (i & 3) * 16);
  }
}

// 8 f32 -> bf16 hi + bf16 lo(residual)
__device__ __forceinline__ void cvt8_hilo(const float* p, bf16x8* h8, bf16x8* l8) {
  union { unsigned short u[8]; bf16x8 v; } uh, ul;
#pragma unroll
  for (int i = 0; i < 8; ++i) {
    float v = p[i];
    __hip_bfloat16 h = __float2bfloat16(v);
    uh.u[i] = *(unsigned short*)&h;
    float rem = v - __bfloat162float(h);
    __hip_bfloat16 l = __float2bfloat16(rem);
    ul.u[i] = *(unsigned short*)&l;
  }
  *h8 = uh.v;
  *l8 = ul.v;
}

// ---------------- embedding gather -> bf16, xe[t*16+b][512] ----------------
__global__ void embed_k(const int* __restrict__ x, const float* __restrict__ emb,
                        unsigned short* __restrict__ xe) {
  int bid = blockIdx.x;  // = t*16 + b
  int t = bid >> 4, b = bid & 15;
  int tok = x[b * SEQ + t];
  const float4* src = (const float4*)(emb + (size_t)tok * HID);
  int e = threadIdx.x;
  float4 a = src[e * 2], c = src[e * 2 + 1];
  uint4 o;
  o.x = pk2(a.x, a.y); o.y = pk2(a.z, a.w);
  o.z = pk2(c.x, c.y); o.w = pk2(c.z, c.w);
  ((uint4*)(xe + (size_t)bid * HID))[e] = o;
}

// ---------------- gx GEMM: gx[4096][2048] bf16 = xe @ Wih0^T (B cvt inline) ----------------
__global__ __launch_bounds__(256) void gx_gemm(const __hip_bfloat16* __restrict__ A,
                                               const float* __restrict__ Bw32,
                                               unsigned short* __restrict__ C) {
  __shared__ __align__(16) unsigned short lds_a[128 * 32];
  __shared__ __align__(16) unsigned short lds_b[128 * 32];
  const int tid = threadIdx.x;
  const int lane = tid & 63, wid = tid >> 6;
  const int m0 = blockIdx.y * 128, n0 = blockIdx.x * 128;
  const char* Ab = (const char*)A;
  const int ra = tid >> 2, cb = (tid & 3) * 16;
  f32x4 acc[4][4] = {};
  const int wm = (wid >> 1) * 64, wn = (wid & 1) * 64;
  const int fr = lane & 15, fk = (lane >> 4) * 8;
  for (int k0 = 0; k0 < HID; k0 += 32) {
    ld_lds16(Ab + (size_t)(m0 + ra) * 1024 + k0 * 2 + cb, (char*)lds_a + wid * 1024);
    ld_lds16(Ab + (size_t)(m0 + 64 + ra) * 1024 + k0 * 2 + cb, (char*)lds_a + 4096 + wid * 1024);
    {
      const float* p0 = Bw32 + (size_t)(n0 + ra) * HID + k0 + (tid & 3) * 8;
      const float* p1 = p0 + (size_t)64 * HID;
      float4 a0 = ((const float4*)p0)[0], a1 = ((const float4*)p0)[1];
      float4 b0 = ((const float4*)p1)[0], b1 = ((const float4*)p1)[1];
      uint4 pa = {pk2(a0.x, a0.y), pk2(a0.z, a0.w), pk2(a1.x, a1.y), pk2(a1.z, a1.w)};
      uint4 pb = {pk2(b0.x, b0.y), pk2(b0.z, b0.w), pk2(b1.x, b1.y), pk2(b1.z, b1.w)};
      ((uint4*)lds_b)[tid] = pa;
      ((uint4*)lds_b)[256 + tid] = pb;
    }
    __syncthreads();
    bf16x8 af[4], bf[4];
#pragma unroll
    for (int i = 0; i < 4; ++i) af[i] = *(const bf16x8*)&lds_a[(wm + i * 16 + fr) * 32 + fk];
#pragma unroll
    for (int j = 0; j < 4; ++j) bf[j] = *(const bf16x8*)&lds_b[(wn + j * 16 + fr) * 32 + fk];
#pragma unroll
    for (int i = 0; i < 4; ++i)
#pragma unroll
      for (int j = 0; j < 4; ++j)
        acc[i][j] = __builtin_amdgcn_mfma_f32_16x16x32_bf16(af[i], bf[j], acc[i][j], 0, 0, 0);
    __syncthreads();
  }
  const int cr = (lane >> 4) * 4, cc2 = lane & 15;
#pragma unroll
  for (int i = 0; i < 4; ++i)
#pragma unroll
    for (int jj = 0; jj < 4; ++jj) {
      size_t base = (size_t)(m0 + wm + i * 16 + cr) * 2048 + (n0 + wn + jj * 16 + cc2);
#pragma unroll
      for (int rr = 0; rr < 4; ++rr) {
        __hip_bfloat16 h = __float2bfloat16(acc[i][jj][rr]);
        C[base + (size_t)rr * 2048] = *(unsigned short*)&h;
      }
    }
}

// ---------------- mega kernel: blocks 0-255 = R7 lstm; 256-1023 = fc workers ----------------
// lstm (R7 verbatim + fast gates + setprio + sc1 outs + lag-flags):
//   lay = bid>>7, r8 = bid&127, 4 h-cols/block, 4 waves split-K, tag-u64 handoff rings.
//   L1 wave0 posts flags[t-1] (after vmcnt(0) drain) during step t; flags[255] after loop.
// fc worker: contiguous tile chunk; per tile poll flags[m*8..m*8+8) >= 128, then m97 tile
//   (A = outs via global_load_lds; B = fcw f32 -> bf16 inline; C row-permuted + bias).
__global__ __launch_bounds__(256) void mega_k(
    const float* __restrict__ Wih, const float* __restrict__ Whh,
    const float* __restrict__ bias, const unsigned short* __restrict__ gxb,
    u64* __restrict__ h0r, u64* __restrict__ h1r, unsigned short* __restrict__ outs,
    unsigned* __restrict__ flags, const float* __restrict__ fcw,
    const float* __restrict__ fcb, float* __restrict__ C) {
  __shared__ __align__(16) char smem[16384];
  __shared__ int ready;
  const int bid = blockIdx.x;
  const int tid = threadIdx.x;
  const int lane = tid & 63, wid = tid >> 6;

  if (bid < 256) {
    // ================= LSTM path =================
    __builtin_amdgcn_s_setprio(1);
    float (*pbuf)[16][17] = (float(*)[16][17])smem;
    const int lay = bid >> 7, r8 = bid & 127;
    const int hc0 = r8 * 4;
    const int b16 = lane & 15, hi = lane >> 4;

    const int jrow = (b16 >> 2) * HID + hc0 + (b16 & 3);
    const int kb = wid * 128 + hi * 8;
    const float* wih_row = Wih + ((size_t)lay * 2048 + jrow) * HID;
    const float* whh_row = Whh + ((size_t)lay * 2048 + jrow) * HID;
    bf16x8 w0[4], w1[4], w2[4], w3[4];
#pragma unroll
    for (int s = 0; s < 4; ++s) {
      if (lay == 0) {
        cvt8_hilo(whh_row + kb + s * 32, &w0[s], &w1[s]);
        w2[s] = w0[s]; w3[s] = w1[s];
      } else {
        cvt8_hilo(wih_row + kb + s * 32, &w0[s], &w1[s]);
        cvt8_hilo(whh_row + kb + s * 32, &w2[s], &w3[s]);
      }
    }
    const int eb = lane & 15, ehl = lane >> 4;
    float bq[4];
#pragma unroll
    for (int q = 0; q < 4; ++q) bq[q] = bias[lay * 2048 + q * HID + hc0 + ehl];
    float c_reg = 0.f;
    const int lbase = wid * 1024 + hi * 64 + b16;

#pragma unroll 1
    for (int t = 0; t < SEQ; ++t) {
      f32x4 acc0 = {0.f, 0.f, 0.f, 0.f}, acc1 = {0.f, 0.f, 0.f, 0.f};
      float gxr[4] = {0.f, 0.f, 0.f, 0.f};
      if (lay == 0) {
        const u64* srcA = h0r + (size_t)t * 4096 + lbase;  // h0[t-1], tag t
        u64 qa[16];
        issue16(qa, srcA);
        if (wid == 0) {
          const unsigned short* gp = gxb + ((size_t)(t * 16 + eb)) * 2048 + hc0 + ehl;
#pragma unroll
          for (int q = 0; q < 4; ++q) {
            union { unsigned u; float f; } cv;
            cv.u = (unsigned)gp[q * HID] << 16;
            gxr[q] = cv.f;
          }
          asm volatile("" : "+v"(gxr[0]), "+v"(gxr[1]), "+v"(gxr[2]), "+v"(gxr[3]));
        }
        revalidate16(qa, srcA, (unsigned)t);
#pragma unroll
        for (int s = 0; s < 4; ++s) {
          union { unsigned u[4]; bf16x8 v; } bb;
#pragma unroll
          for (int j = 0; j < 4; ++j) bb.u[j] = (unsigned)qa[s * 4 + j];
          acc0 = __builtin_amdgcn_mfma_f32_16x16x32_bf16(w0[s], bb.v, acc0, 0, 0, 0);
          acc1 = __builtin_amdgcn_mfma_f32_16x16x32_bf16(w1[s], bb.v, acc1, 0, 0, 0);
        }
      } else {
        const u64* srcA = h0r + (size_t)(t + 1) * 4096 + lbase;  // h0[t], tag t+1
        const u64* srcB = h1r + (size_t)t * 4096 + lbase;        // h1[t-1], tag t
        u64 qb[16], qa[16];
        issue16(qb, srcB);
        issue16(qa, srcA);
        revalidate16(qb, srcB, (unsigned)t);
#pragma unroll
        for (int s = 0; s < 4; ++s) {
          union { unsigned u[4]; bf16x8 v; } bb;
#pragma unroll
          for (int j = 0; j < 4; ++j) bb.u[j] = (unsigned)qb[s * 4 + j];
          acc0 = __builtin_amdgcn_mfma_f32_16x16x32_bf16(w2[s], bb.v, acc0, 0, 0, 0);
          acc1 = __builtin_amdgcn_mfma_f32_16x16x32_bf16(w3[s], bb.v, acc1, 0, 0, 0);
        }
        revalidate16(qa, srcA, (unsigned)(t + 1));
#pragma unroll
        for (int s = 0; s < 4; ++s) {
          union { unsigned u[4]; bf16x8 v; } bb;
#pragma unroll
          for (int j = 0; j < 4; ++j) bb.u[j] = (unsigned)qa[s * 4 + j];
          acc0 = __builtin_amdgcn_mfma_f32_16x16x32_bf16(w0[s], bb.v, acc0, 0, 0, 0);
          acc1 = __builtin_amdgcn_mfma_f32_16x16x32_bf16(w1[s], bb.v, acc1, 0, 0, 0);
        }
      }
      f32x4 acc = acc0 + acc1;
#pragma unroll
      for (int rr = 0; rr < 4; ++rr) pbuf[wid][hi * 4 + rr][b16] = acc[rr];
      __syncthreads();

      if (wid == 0) {
        if (lay) {  // lag-flag: post t-1 after draining its stores (they're ~1 step old)
          asm volatile("s_waitcnt vmcnt(0)" ::: "memory");
          if (lane == 0 && t > 0)
            __hip_atomic_fetch_add(flags + (size_t)(t - 1) * 16, 1u, __ATOMIC_RELAXED,
                                   __HIP_MEMORY_SCOPE_AGENT);
        }
        float pre[4];
#pragma unroll
        for (int q = 0; q < 4; ++q) {
          const int rl = q * 4 + ehl;
          pre[q] = bq[q] + gxr[q] + pbuf[0][rl][eb] + pbuf[1][rl][eb] +
                   pbuf[2][rl][eb] + pbuf[3][rl][eb];
        }
        float iv = fsig(pre[0]), fv = fsig(pre[1]);
        float gv = ftanh(pre[2]), ov = fsig(pre[3]);
        c_reg = fv * c_reg + iv * gv;
        float hn = ov * ftanh(c_reg);
        __hip_bfloat16 hh = __float2bfloat16(hn);
        int hb = (int)*(unsigned short*)&hh;
        int pr = __shfl_xor(hb, 16, 64);  // col ^ 1
        unsigned data32 = (unsigned)(unsigned short)hb | ((unsigned)(unsigned short)pr << 16);
        u64* ringo = (lay ? h1r : h0r) + (size_t)(t + 1) * 4096;
        if ((ehl & 1) == 0)
          agstore(ringo + (r8 * 2 + (ehl >> 1)) * 16 + eb,
                  (u64)data32 | ((u64)(unsigned)(t + 1) << 32));
        if (lay) {
          unsigned d23 = (unsigned)__shfl((int)data32, eb + 32, 64);
          if (ehl == 0)
            agstore((u64*)(outs + ((size_t)(t * 16 + eb)) * 512 + hc0),
                    (u64)data32 | ((u64)d23 << 32));
        }
      }
      __syncthreads();  // pbuf reuse guard
    }
    if (lay == 1 && wid == 0) {  // final flag
      asm volatile("s_waitcnt vmcnt(0)" ::: "memory");
      if (lane == 0)
        __hip_atomic_fetch_add(flags + (size_t)(SEQ - 1) * 16, 1u, __ATOMIC_RELAXED,
                               __HIP_MEMORY_SCOPE_AGENT);
    }
  } else {
    // ================= FC worker path =================
    unsigned short* lds_a = (unsigned short*)smem;
    unsigned short* lds_b = lds_a + 4096;
    const int wrk = bid - 256;  // 0..767
    const int t0 = wrk * 8000 / 768, t1 = (wrk + 1) * 8000 / 768;
    const int ra = tid >> 2, cbyt = (tid & 3) * 16;
    const int wm = (wid >> 1) * 64, wn = (wid & 1) * 64;
    const int fr = lane & 15, fk = (lane >> 4) * 8;
    for (int tau = t0; tau < t1; ++tau) {
      const int m = tau / 250, n = tau - m * 250;
      const int m0 = m * 128, n0 = n * 128;
      // ---- poll readiness of tokens [m*8, m*8+8) ----
      for (;;) {
        int ok = 1;
        if (tid < 8) {
          unsigned f = __hip_atomic_load(flags + (size_t)(m * 8 + tid) * 16,
                                         __ATOMIC_RELAXED, __HIP_MEMORY_SCOPE_AGENT);
          ok = (f >= 128u);
        }
        int allok = __all(ok);
        if (tid == 0) ready = allok;
        __syncthreads();
        int rd = ready;
        __syncthreads();
        if (rd) break;
        __builtin_amdgcn_s_sleep(64);
      }
      // ---- m97 tile: A = outs (bf16), B = fcw f32 cvt inline ----
      const char* Ab = (const char*)outs;
      f32x4 acc[4][4] = {};
      for (int k0 = 0; k0 < HID; k0 += 32) {
        ld_lds16(Ab + (size_t)(m0 + ra) * 1024 + k0 * 2 + cbyt, (char*)lds_a + wid * 1024);
        ld_lds16(Ab + (size_t)(m0 + 64 + ra) * 1024 + k0 * 2 + cbyt,
                 (char*)lds_a + 4096 + wid * 1024);
        {
          const float* p0 = fcw + (size_t)(n0 + ra) * HID + k0 + (tid & 3) * 8;
          const float* p1 = p0 + (size_t)64 * HID;
          float4 a0 = ((const float4*)p0)[0], a1 = ((const float4*)p0)[1];
          float4 b0 = ((const float4*)p1)[0], b1 = ((const float4*)p1)[1];
          uint4 pa = {pk2(a0.x, a0.y), pk2(a0.z, a0.w), pk2(a1.x, a1.y), pk2(a1.z, a1.w)};
          uint4 pb = {pk2(b0.x, b0.y), pk2(b0.z, b0.w), pk2(b1.x, b1.y), pk2(b1.z, b1.w)};
          ((uint4*)lds_b)[tid] = pa;
          ((uint4*)lds_b)[256 + tid] = pb;
        }
        __syncthreads();
        bf16x8 af[4], bf[4];
#pragma unroll
        for (int i = 0; i < 4; ++i) af[i] = *(const bf16x8*)&lds_a[(wm + i * 16 + fr) * 32 + fk];
#pragma unroll
        for (int j = 0; j < 4; ++j) bf[j] = *(const bf16x8*)&lds_b[(wn + j * 16 + fr) * 32 + fk];
#pragma unroll
        for (int i = 0; i < 4; ++i)
#pragma unroll
          for (int j = 0; j < 4; ++j)
            acc[i][j] = __builtin_amdgcn_mfma_f32_16x16x32_bf16(af[i], bf[j], acc[i][j], 0, 0, 0);
        __syncthreads();
      }
      const int cr = (lane >> 4) * 4, cc2 = lane & 15;
      float bv[4];
#pragma unroll
      for (int jj = 0; jj < 4; ++jj) bv[jj] = fcb[n0 + wn + jj * 16 + cc2];
#pragma unroll
      for (int i = 0; i < 4; ++i) {
#pragma unroll
        for (int jj = 0; jj < 4; ++jj) {
#pragma unroll
          for (int rr = 0; rr < 4; ++rr) {
            int tok = m0 + wm + i * 16 + cr + rr;      // = t*16 + b
            int orow = (tok & 15) * SEQ + (tok >> 4);  // = b*256 + t
            C[(size_t)orow * VOC + (n0 + wn + jj * 16 + cc2)] = acc[i][jj][rr] + bv[jj];
          }
        }
      }
    }
  }
}

extern "C" void kernel_launch(void* const* d_in, const int* in_sizes, int n_in,
                              void* d_out, int out_size, void* d_ws, size_t ws_size,
                              hipStream_t stream) {
  const int* x = (const int*)d_in[0];
  const float* emb = (const float*)d_in[1];
  const float* Wih = (const float*)d_in[2];
  const float* Whh = (const float*)d_in[3];
  const float* bias = (const float*)d_in[4];
  const float* fcw = (const float*)d_in[5];
  const float* fcb = (const float*)d_in[6];
  float* out = (float*)d_out;
  char* ws = (char*)d_ws;

  // ws layout (bytes), total 42,024,960:
  //   [0, 16384)              flags[256] @ 64B stride (outs readiness, count to 128)
  //   [16384, 8437760)        h0 ring: 257 slots x 32KB (u64 = 2 bf16 cols + tag)
  //   [8437760, 16859136)     h1 ring: 257 slots x 32KB
  //   [16859136, 21053440)    xe[4096][512] bf16 (dead after gx_gemm)
  //   [21053440, 37830656)    gx bf16 [4096][2048]
  //   [37830656, 42024960)    outs[4096][512] bf16 (dedicated; sc1-written, fc-read)
  unsigned* flags = (unsigned*)ws;
  u64* h0r = (u64*)(ws + 16384);
  u64* h1r = (u64*)(ws + 8437760);
  unsigned short* xe = (unsigned short*)(ws + 16859136);
  unsigned short* gxb = (unsigned short*)(ws + 21053440);
  unsigned short* outs = (unsigned short*)(ws + 37830656);

  hipMemsetAsync(ws, 0, 16859136, stream);  // flags + both rings (tags=0, h[-1]=0)
  embed_k<<<SEQ * NB, 64, 0, stream>>>(x, emb, xe);
  gx_gemm<<<dim3(16, 32), 256, 0, stream>>>((const __hip_bfloat16*)xe, Wih, gxb);
  mega_k<<<1024, 256, 0, stream>>>(Wih, Whh, bias, gxb, h0r, h1r, outs, flags, fcw, fcb, out);
}